// Round 1
// baseline (7624.108 us; speedup 1.0000x reference)
//
#include <hip/hip_runtime.h>

// ---------------- static schedule tables (derived from _proj_shapes trace) ----------------
__device__ const int g_uprev[2][6] = {{1,4,4,4,4,4},{1,4,8,8,8,4}};
__device__ const int g_dprev[2][6] = {{4,4,4,4,4,1},{4,8,8,8,4,1}};
__device__ const int g_mtab[2][5]  = {{16,16,16,16,16},{16,32,32,32,16}};
__device__ const int g_cbtab[5]    = {4,8,8,8,4};
__device__ const int g_ucurtab[5]  = {1,4,8,8,8};
__device__ const int g_dntab[2][5] = {{16,16,16,16,1},{32,32,32,16,1}};
__device__ const int g_offtab[4][5]= {{0,128,384,640,896},
                                      {1024,1152,1664,2176,2688},
                                      {2816,2944,3456,3968,4480},
                                      {4608,4736,5248,5760,6272}};
__device__ const int g_ufin[6] = {1,4,8,8,8,4};
__device__ const int g_dfin[6] = {4,8,8,8,4,1};

// ============ kernel 1: pert[s][k] = ETA*(relu(x W1^T + b1) W2^T + b2) into ws ============
__global__ __launch_bounds__(256) void mlp_kernel(
    const float* __restrict__ W1, const float* __restrict__ b1,
    const float* __restrict__ W2, const float* __restrict__ b2,
    const int* __restrict__ x, float* __restrict__ proj)
{
  __shared__ float hbuf[8][64];
  const int tid = threadIdx.x;
  const int s0 = blockIdx.x << 3;  // 8 samples per block
  for (int e = tid; e < 512; e += 256) {
    const int sl = e >> 6, hh = e & 63;
    const int* xr = x + (s0 + sl) * 36;
    const float* wr = W1 + hh * 36;
    float acc = b1[hh];
    #pragma unroll
    for (int t = 0; t < 36; ++t) acc += wr[t] * (float)xr[t];
    hbuf[sl][hh] = fmaxf(acc, 0.0f);
  }
  __syncthreads();
  for (int k = tid; k < 6400; k += 256) {
    const float4* wr = (const float4*)(W2 + (size_t)k * 64);
    float acc[8];
    #pragma unroll
    for (int s2 = 0; s2 < 8; ++s2) acc[s2] = 0.0f;
    #pragma unroll
    for (int c = 0; c < 16; ++c) {
      const float4 w = wr[c];
      #pragma unroll
      for (int s2 = 0; s2 < 8; ++s2) {
        const float4 hv = ((const float4*)hbuf[s2])[c];
        acc[s2] += w.x * hv.x + w.y * hv.y + w.z * hv.z + w.w * hv.w;
      }
    }
    const float bb = b2[k];
    #pragma unroll
    for (int s2 = 0; s2 < 8; ++s2)
      proj[(size_t)(s0 + s2) * 6400 + k] = 0.001f * (acc[s2] + bb);
  }
}

// ============ symmetric Jacobi eigensolver, N in {16,32}, 128 threads ============
// hm: NxN (stride 32) in/out (diag -> eigenvalues). vv: eigenvectors in COLUMNS (stride 32).
template<int N>
__device__ __forceinline__ void jacobi_eig(
    float* __restrict__ hm, float* __restrict__ vv,
    float* coefC, float* coefS, int* part, float* red, int tid)
{
  constexpr int NLOG = (N == 32) ? 5 : 4;
  constexpr int CNT  = (N * N) / 128;
  constexpr int NP   = N / 2;
  const int MAXSW = (N == 32) ? 10 : 9;

  for (int e = tid; e < N * N; e += 128) {
    const int i2 = e >> NLOG, jc = e & (N - 1);
    vv[i2 * 32 + jc] = (i2 == jc) ? 1.0f : 0.0f;
  }
  for (int sw = 0; sw < MAXSW; ++sw) {
    for (int rd = 0; rd < N - 1; ++rd) {
      __syncthreads();
      if (tid < NP) {  // round-robin tournament pairing + rotation angles
        const int nm1 = N - 1;
        int p_, q_;
        if (tid == 0) { p_ = nm1; q_ = rd % nm1; }
        else { p_ = (rd + tid) % nm1; q_ = (rd - tid + 2 * nm1) % nm1; }
        const int p = p_ < q_ ? p_ : q_;
        const int q = p_ < q_ ? q_ : p_;
        const float app = hm[p * 32 + p];
        const float aqq = hm[q * 32 + q];
        const float apq = hm[p * 32 + q];
        float c = 1.0f, sn = 0.0f;
        if (fabsf(apq) > 1e-36f + 1e-12f * (fabsf(app) + fabsf(aqq))) {
          const float tau = (aqq - app) / (2.0f * apq);
          const float t = copysignf(1.0f, tau) / (fabsf(tau) + sqrtf(1.0f + tau * tau));
          c = 1.0f / sqrtf(1.0f + t * t);
          sn = t * c;
        }
        coefC[p] = c; coefS[p] = -sn; part[p] = q;
        coefC[q] = c; coefS[q] =  sn; part[q] = p;
      }
      __syncthreads();
      // fused G' = J^T G J and V' = V J (all reads from old values)
      float gnew[CNT], vnew[CNT];
      #pragma unroll
      for (int t = 0; t < CNT; ++t) {
        const int e = tid + t * 128;
        const int i2 = e >> NLOG, jc = e & (N - 1);
        const int pi = part[i2], pj = part[jc];
        const float ci = coefC[i2], si = coefS[i2];
        const float cj = coefC[jc], sj = coefS[jc];
        const float g_ij  = hm[i2 * 32 + jc];
        const float g_ipj = hm[i2 * 32 + pj];
        const float g_pij = hm[pi * 32 + jc];
        const float g_ppj = hm[pi * 32 + pj];
        const float t1 = ci * g_ij  + si * g_pij;
        const float t2 = ci * g_ipj + si * g_ppj;
        gnew[t] = cj * t1 + sj * t2;
        vnew[t] = cj * vv[i2 * 32 + jc] + sj * vv[i2 * 32 + pj];
      }
      __syncthreads();
      #pragma unroll
      for (int t = 0; t < CNT; ++t) {
        const int e = tid + t * 128;
        const int i2 = e >> NLOG, jc = e & (N - 1);
        hm[i2 * 32 + jc] = gnew[t];
        vv[i2 * 32 + jc] = vnew[t];
      }
    }
    // early exit on relative off-diagonal norm
    __syncthreads();
    float offs = 0.0f, dia = 0.0f;
    #pragma unroll
    for (int t = 0; t < CNT; ++t) {
      const int e = tid + t * 128;
      const int i2 = e >> NLOG, jc = e & (N - 1);
      const float v_ = hm[i2 * 32 + jc];
      if (i2 == jc) dia += v_ * v_; else offs += v_ * v_;
    }
    for (int mk = 32; mk; mk >>= 1) {
      offs += __shfl_xor(offs, mk);
      dia  += __shfl_xor(dia, mk);
    }
    if ((tid & 63) == 0) { red[(tid >> 6) * 2] = offs; red[(tid >> 6) * 2 + 1] = dia; }
    __syncthreads();
    const float to = red[0] + red[2];
    const float td = red[1] + red[3];
    if (to <= 1e-12f * td) break;
  }
  __syncthreads();
}

// ============ absorb row (i,j): dst[u*ad+a][R][d*bd+b] = sum_x OLD[u][x][d]*A[a][R][b][x] ============
__device__ __forceinline__ void absorb_row(
    const float* __restrict__ Tg, const float* oldP, float* dst,
    int i, int j, int U, int Dd, const int* xi, float* Als, int tid)
{
  const int ad = (i == 0) ? 1 : 4, bd = (i == 5) ? 1 : 4;
  const int ph = xi[i * 6 + j];
  const float* tb = Tg + (size_t)(i * 6 + j) * 512;
  for (int e = tid; e < 256; e += 128) Als[e] = tb[e * 2 + ph];  // [a][R][b][x]
  __syncthreads();
  const int dbw = Dd * bd;
  const int dblog = 31 - __clz(dbw);
  const int adlog = (ad == 4) ? 2 : 0, bdlog = (bd == 4) ? 2 : 0;
  const int nel = U * ad * 4 * dbw;
  for (int e = tid; e < nel; e += 128) {
    const int db = e & (dbw - 1);
    const int rr = (e >> dblog) & 3;
    const int ua = e >> (dblog + 2);
    const int u = ua >> adlog, a = ua & (ad - 1);
    const int d_ = db >> bdlog, b = db & (bd - 1);
    const float* op = oldP + i * 256 + u * 32 + d_;           // stride: u*32 + x*8 + d
    const float4 av = *(const float4*)(Als + a * 64 + rr * 16 + b * 4);
    dst[ua * 128 + rr * 32 + db] = op[0] * av.x + op[8] * av.y + op[16] * av.z + op[24] * av.w;
  }
  __syncthreads();
}

// ============ one truncation pair (i,i+1): Gram -> chol -> H -> eigen -> Pd/Pu -> updates ============
__device__ __forceinline__ void truncate_pair(
    int i, int m, int cb, int ucur, int dn, bool do_svd,
    float* __restrict__ projbase,
    float* CUR, float* BIG, float* finP,
    float* Gt, float* GbX, float* R2m, float* Hm,
    float* Pd, float* Pu,
    float* coefC, float* coefS, int* part,
    int* isel, float* sinvv, float* spui,
    float* red, int tid)
{
  const int mlog = (m == 32) ? 5 : 4;
  const int cblog = (cb == 8) ? 3 : 2;
  if (do_svd) {
    const int p = ucur * 4;
    // Gt = mt^T mt  (mt = CUR reshaped (ucur*4, m))
    for (int e = tid; e < m * m; e += 128) {
      const int al = e >> mlog, be = e & (m - 1);
      float acc = 0.0f;
      for (int row = 0; row < p; ++row) {
        const int bo = (row >> 2) * 128 + (row & 3) * 32;
        acc += CUR[bo + al] * CUR[bo + be];
      }
      Gt[al * 32 + be] = acc;
    }
    // Gb = mb mb^T  (mb = BIG reshaped (m, 4*dn))
    for (int e = tid; e < m * m; e += 128) {
      const int al = e >> mlog, be = e & (m - 1);
      float acc = 0.0f;
      if (dn >= 4) {
        #pragma unroll
        for (int rr = 0; rr < 4; ++rr) {
          const float4* ra = (const float4*)(BIG + al * 128 + rr * 32);
          const float4* rb = (const float4*)(BIG + be * 128 + rr * 32);
          for (int dq = 0; dq < (dn >> 2); ++dq) {
            const float4 a4 = ra[dq], b4 = rb[dq];
            acc += a4.x * b4.x + a4.y * b4.y + a4.z * b4.z + a4.w * b4.w;
          }
        }
      } else {
        #pragma unroll
        for (int rr = 0; rr < 4; ++rr)
          acc += BIG[al * 128 + rr * 32] * BIG[be * 128 + rr * 32];
      }
      GbX[al * 32 + be] = acc;
    }
    __syncthreads();
    // max diag for pivot tolerance
    if (tid < 64) {
      float v_ = (tid < m) ? GbX[tid * 33] : -3e38f;
      for (int mk = 32; mk; mk >>= 1) v_ = fmaxf(v_, __shfl_xor(v_, mk));
      if (tid == 0) red[0] = v_;
    }
    __syncthreads();
    const float thr = 1e-10f * red[0] + 1e-35f;
    // unpivoted PSD Cholesky with zero-skip: Gb = R2^T R2 (R2 rows in R2m, stride 32)
    for (int k = 0; k < m; ++k) {
      const float dk = GbX[k * 33];
      const float rs = (dk > thr) ? (1.0f / sqrtf(dk)) : 0.0f;
      if (tid < m) R2m[k * 32 + tid] = GbX[k * 32 + tid] * rs;
      __syncthreads();
      const int rows = m - 1 - k;
      for (int e = tid; e < rows * m; e += 128) {
        const int ii = k + 1 + (e >> mlog);
        const int jc = e & (m - 1);
        GbX[ii * 32 + jc] -= R2m[k * 32 + ii] * R2m[k * 32 + jc];
      }
      __syncthreads();
    }
    // T1 = R2 * Gt  (into GbX, Gb dead)
    for (int e = tid; e < m * m; e += 128) {
      const int k = e >> mlog, jc = e & (m - 1);
      float acc = 0.0f;
      for (int l = 0; l < m; ++l) acc += R2m[k * 32 + l] * Gt[l * 32 + jc];
      GbX[k * 32 + jc] = acc;
    }
    __syncthreads();
    // H = T1 * R2^T  = M^T M (same spectrum/projectors as reference SVD)
    for (int e = tid; e < m * m; e += 128) {
      const int k = e >> mlog, k2 = e & (m - 1);
      float acc = 0.0f;
      for (int l = 0; l < m; ++l) acc += GbX[k * 32 + l] * R2m[k2 * 32 + l];
      Hm[k * 32 + k2] = acc;
    }
    __syncthreads();
    if (m == 32) jacobi_eig<32>(Hm, GbX, coefC, coefS, part, red, tid);  // V -> GbX
    else         jacobi_eig<16>(Hm, GbX, coefC, coefS, part, red, tid);
    // top-cb eigenpairs (descending, stable tie-break)
    if (tid < 64) {
      float v_ = (tid < m) ? Hm[tid * 33] : -3e38f;
      int ix = tid;
      for (int t = 0; t < cb; ++t) {
        float bv = v_; int bi = ix;
        for (int mk = 32; mk; mk >>= 1) {
          const float ov = __shfl_xor(bv, mk);
          const int oi = __shfl_xor(bi, mk);
          if (ov > bv || (ov == bv && oi < bi)) { bv = ov; bi = oi; }
        }
        if (tid == 0) isel[t] = bi;
        if (ix == bi) v_ = -3e38f;
      }
    }
    __syncthreads();
    if (tid < cb) {
      const float lam = Hm[isel[tid] * 33];
      const float s_ = sqrtf(fmaxf(lam, 0.0f));
      sinvv[tid] = 1.0f / sqrtf(s_ + 1e-12f);   // matches reference 1/sqrt(S+1e-12)
      spui[tid]  = 1.0f / fmaxf(s_, 1e-25f);
    }
    __syncthreads();
    // Pd[:,k] = R2^T V_k * sinv_k
    for (int e = tid; e < m * cb; e += 128) {
      const int jj2 = e >> cblog, k = e & (cb - 1);
      const int a = isel[k];
      float acc = 0.0f;
      for (int t2 = 0; t2 < m; ++t2) acc += R2m[t2 * 32 + jj2] * GbX[t2 * 32 + a];
      Pd[jj2 * 8 + k] = acc * sinvv[k];
    }
    __syncthreads();
    // Pu[:,k] = Gt Pd_k / s_k   (== R1^T U_k * sinv_k exactly)
    for (int e = tid; e < m * cb; e += 128) {
      const int jj2 = e >> cblog, k = e & (cb - 1);
      float acc = 0.0f;
      for (int l = 0; l < m; ++l) acc += Gt[jj2 * 32 + l] * Pd[l * 8 + k];
      Pu[jj2 * 8 + k] = acc * spui[k];
    }
    __syncthreads();
    // perturbed projector write: ws slot already holds ETA*mlp
    for (int e = tid; e < m * cb; e += 128) {
      const int jj2 = e >> cblog, k = e & (cb - 1);
      projbase[e] += Pd[jj2 * 8 + k];
      projbase[m * cb + e] += Pu[jj2 * 8 + k];
    }
  } else {
    // sweep 2: load perturbed projectors
    for (int e = tid; e < m * cb; e += 128) {
      const int jj2 = e >> cblog, k = e & (cb - 1);
      Pd[jj2 * 8 + k] = projbase[e];
      Pu[jj2 * 8 + k] = projbase[m * cb + e];
    }
    __syncthreads();
  }
  // Bn[i] = einsum('uRm,mc->uRc', Tt, Pd) -> compressed pool (NOTE: sweep1 uses UNperturbed Pd)
  for (int e = tid; e < ucur * 4 * cb; e += 128) {
    const int cc = e & (cb - 1);
    const int rr = (e >> cblog) & 3;
    const int u = e >> (cblog + 2);
    float acc = 0.0f;
    for (int mm = 0; mm < m; ++mm) acc += CUR[u * 128 + rr * 32 + mm] * Pd[mm * 8 + cc];
    finP[i * 256 + u * 32 + rr * 8 + cc] = acc;
  }
  __syncthreads();
  // Bn[i+1] = einsum('mRd,mc->cRd', Tb, Pu) -> CUR (next Tt), or pool row 5 at the end
  const int dnlog = (dn == 32) ? 5 : ((dn == 16) ? 4 : 0);
  for (int e = tid; e < cb * 4 * dn; e += 128) {
    const int dd = e & (dn - 1);
    const int rr = (e >> dnlog) & 3;
    const int cc = e >> (dnlog + 2);
    float acc = 0.0f;
    for (int mm = 0; mm < m; ++mm) acc += BIG[mm * 128 + rr * 32 + dd] * Pu[mm * 8 + cc];
    if (i < 4) CUR[cc * 128 + rr * 32 + dd] = acc;
    else finP[5 * 256 + cc * 32 + rr * 8] = acc;
  }
  __syncthreads();
}

// ============ kernel 2: one sample per 128-thread workgroup ============
__global__ __launch_bounds__(128) void peps_kernel(
    const float* __restrict__ Tg, const int* __restrict__ x,
    float* __restrict__ proj, float* __restrict__ out)
{
  __shared__ float pool[2 * 1536];   // double-buffered compressed rows: [u<=8][R=4][d<=8] stride (32,8,1)
  __shared__ float CUR[1024];        // current top tensor (u<=8,4,m<=32) stride (128,32,1)
  __shared__ float BIG[4096];        // freshly absorbed row (<=32,4,<=32) stride (128,32,1)
  __shared__ float Gt[1024];
  __shared__ float GbX[1024];        // Gb -> T1 -> V
  __shared__ float R2m[1024];
  __shared__ float Hm[1024];         // H; first 256 floats double as A-tile during absorb/finalize
  __shared__ float Pd[256];
  __shared__ float Pu[256];
  __shared__ float coefC[32], coefS[32];
  __shared__ int part[32];
  __shared__ int isel[8];
  __shared__ float sinvv[8], spui[8];
  __shared__ int xi[36];
  __shared__ float vvec[32], vvec2[32];
  __shared__ float red[4];

  const int s = blockIdx.x;
  const int tid = threadIdx.x;
  if (tid < 36) xi[tid] = x[s * 36 + tid];
  __syncthreads();

  for (int sweep = 0; sweep < 2; ++sweep) {
    int ps = 0;
    // init boundary MPS from row j=0: B[i] = A[i][0][:,:,:,0]
    for (int i = 0; i < 6; ++i) {
      const int ad = (i == 0) ? 1 : 4, bd = (i == 5) ? 1 : 4;
      const int bdlog = (bd == 4) ? 2 : 0;
      const int ph = xi[i * 6 + 0];
      const float* tb = Tg + (size_t)(i * 6 + 0) * 512;
      const int nel = ad * 4 * bd;
      for (int e = tid; e < nel; e += 128) {
        const int b = e & (bd - 1);
        const int rr = (e >> bdlog) & 3;
        const int a = e >> (bdlog + 2);
        pool[i * 256 + a * 32 + rr * 8 + b] = tb[(a * 64 + rr * 16 + b * 4) * 2 + ph];
      }
    }
    __syncthreads();
    for (int j = 1; j <= 4; ++j) {
      const int jj = (j > 1) ? 1 : 0;
      float* oldP = pool + ps * 1536;
      float* finP = pool + (ps ^ 1) * 1536;
      absorb_row(Tg, oldP, CUR, 0, j, g_uprev[jj][0], g_dprev[jj][0], xi, Hm, tid);
      for (int i = 0; i < 5; ++i) {
        absorb_row(Tg, oldP, BIG, i + 1, j, g_uprev[jj][i + 1], g_dprev[jj][i + 1], xi, Hm, tid);
        truncate_pair(i, g_mtab[jj][i], g_cbtab[i], g_ucurtab[i], g_dntab[jj][i],
                      (sweep == 0),
                      proj + (size_t)s * 6400 + g_offtab[j - 1][i],
                      CUR, BIG, finP, Gt, GbX, R2m, Hm, Pd, Pu,
                      coefC, coefS, part, isel, sinvv, spui, red, tid);
      }
      ps ^= 1;
    }
    if (sweep == 1) {
      // finalize: v = prod_i C_i, C_i = einsum('uxd,abx->uadb', B[i], A[i][5][:,0])
      const float* finB = pool + ps * 1536;
      if (tid == 0) vvec[0] = 1.0f;
      __syncthreads();
      for (int i = 0; i < 6; ++i) {
        const int ad = (i == 0) ? 1 : 4, bd = (i == 5) ? 1 : 4;
        const int adlog = (ad == 4) ? 2 : 0, bdlog = (bd == 4) ? 2 : 0;
        const int rows = g_ufin[i] * ad, cols = g_dfin[i] * bd;
        const int clog = 31 - __clz(cols);
        const int ph = xi[i * 6 + 5];
        const float* tb = Tg + (size_t)(i * 6 + 5) * 512;
        for (int e = tid; e < 256; e += 128) Hm[e] = tb[e * 2 + ph];
        __syncthreads();
        for (int e = tid; e < rows * cols; e += 128) {
          const int col = e & (cols - 1);
          const int ua = e >> clog;
          const int u = ua >> adlog, a = ua & (ad - 1);
          const int d_ = col >> bdlog, b = col & (bd - 1);
          const float* fb = finB + i * 256 + u * 32 + d_;
          const float4 av = *(const float4*)(Hm + a * 64 + b * 4);  // R index = 0 slice
          Gt[ua * 32 + col] = fb[0] * av.x + fb[8] * av.y + fb[16] * av.z + fb[24] * av.w;
        }
        __syncthreads();
        if (tid < cols) {
          float acc = 0.0f;
          for (int r_ = 0; r_ < rows; ++r_) acc += vvec[r_] * Gt[r_ * 32 + tid];
          vvec2[tid] = acc;
        }
        __syncthreads();
        if (tid < cols) vvec[tid] = vvec2[tid];
        __syncthreads();
      }
      if (tid == 0) out[s] = vvec[0];
    }
  }
}

extern "C" void kernel_launch(void* const* d_in, const int* in_sizes, int n_in,
                              void* d_out, int out_size, void* d_ws, size_t ws_size,
                              hipStream_t stream) {
  const float* Tg = (const float*)d_in[0];
  const float* W1 = (const float*)d_in[1];
  const float* b1 = (const float*)d_in[2];
  const float* W2 = (const float*)d_in[3];
  const float* b2 = (const float*)d_in[4];
  const int*   x  = (const int*)d_in[5];
  float* out = (float*)d_out;
  float* proj = (float*)d_ws;   // 1024*6400 floats = 26.2 MB: ETA*mlp, then += projectors
  (void)in_sizes; (void)n_in; (void)out_size; (void)ws_size;

  mlp_kernel<<<dim3(128), dim3(256), 0, stream>>>(W1, b1, W2, b2, x, proj);
  peps_kernel<<<dim3(1024), dim3(128), 0, stream>>>(Tg, x, proj, out);
}

// Round 2
// 3194.630 us; speedup vs baseline: 2.3865x; 2.3865x over previous
//
#include <hip/hip_runtime.h>

// ---------------- static schedule tables ----------------
__device__ const int g_uprev[2][6] = {{1,4,4,4,4,4},{1,4,8,8,8,4}};
__device__ const int g_dprev[2][6] = {{4,4,4,4,4,1},{4,8,8,8,4,1}};
__device__ const int g_mtab[2][5]  = {{16,16,16,16,16},{16,32,32,32,16}};
__device__ const int g_cbtab[5]    = {4,8,8,8,4};
__device__ const int g_ucurtab[5]  = {1,4,8,8,8};
__device__ const int g_dntab[2][5] = {{16,16,16,16,1},{32,32,32,16,1}};
__device__ const int g_path[2][5]  = {{0,0,1,1,2},{0,0,0,0,2}};  // 0=p-side,1=m-side(chol),2=q-side
__device__ const int g_offtab[4][5]= {{0,128,384,640,896},
                                      {1024,1152,1664,2176,2688},
                                      {2816,2944,3456,3968,4480},
                                      {4608,4736,5248,5760,6272}};
__device__ const int g_ufin[6] = {1,4,8,8,8,4};
__device__ const int g_dfin[6] = {4,8,8,8,4,1};

// ============ kernel 1: proj[s][k] = ETA*mlp(x_s)[k] ============
__global__ __launch_bounds__(256) void mlp_kernel(
    const float* __restrict__ W1, const float* __restrict__ b1,
    const float* __restrict__ W2, const float* __restrict__ b2,
    const int* __restrict__ x, float* __restrict__ proj)
{
  __shared__ float hbuf[8][64];
  const int tid = threadIdx.x;
  const int s0 = blockIdx.x << 3;
  for (int e = tid; e < 512; e += 256) {
    const int sl = e >> 6, hh = e & 63;
    const int* xr = x + (s0 + sl) * 36;
    const float* wr = W1 + hh * 36;
    float acc = b1[hh];
    #pragma unroll
    for (int t = 0; t < 36; ++t) acc += wr[t] * (float)xr[t];
    hbuf[sl][hh] = fmaxf(acc, 0.0f);
  }
  __syncthreads();
  for (int k = tid; k < 6400; k += 256) {
    const float4* wr = (const float4*)(W2 + (size_t)k * 64);
    float acc[8];
    #pragma unroll
    for (int s2 = 0; s2 < 8; ++s2) acc[s2] = 0.0f;
    #pragma unroll
    for (int c = 0; c < 16; ++c) {
      const float4 w = wr[c];
      #pragma unroll
      for (int s2 = 0; s2 < 8; ++s2) {
        const float4 hv = ((const float4*)hbuf[s2])[c];
        acc[s2] += w.x * hv.x + w.y * hv.y + w.z * hv.z + w.w * hv.w;
      }
    }
    const float bb = b2[k];
    #pragma unroll
    for (int s2 = 0; s2 < 8; ++s2)
      proj[(size_t)(s0 + s2) * 6400 + k] = 0.001f * (acc[s2] + bb);
  }
}

// ---------------- small device helpers ----------------
template<int N>
__device__ __forceinline__ void pairpq(int t, int rd, int& p, int& q) {
  const int nm1 = N - 1;
  int a, b;
  if (t == 0) { a = nm1; b = rd % nm1; }
  else { a = (rd + t) % nm1; b = (rd - t + 2 * nm1) % nm1; }
  p = a < b ? a : b;
  q = a < b ? b : a;
}

__device__ __forceinline__ void jrot(float app, float aqq, float apq, float& c, float& sn) {
  c = 1.0f; sn = 0.0f;
  if (fabsf(apq) > 1e-36f + 1e-12f * (fabsf(app) + fabsf(aqq))) {
    const float tau = (aqq - app) / (2.0f * apq);
    const float t = copysignf(1.0f, tau) / (fabsf(tau) + sqrtf(1.0f + tau * tau));
    c = 1.0f / sqrtf(1.0f + t * t);
    sn = t * c;
  }
}

// pair-blocked two-sided Jacobi; H,V stride-36; diag -> eigenvalues; V columns = eigvecs
template<int N>
__device__ void jacobi_pb(float* __restrict__ H, float* __restrict__ V,
                          float* __restrict__ red, int tid)
{
  constexpr int NP = N / 2;
  constexpr int NL = (N == 32) ? 5 : ((N == 16) ? 4 : 2);
  constexpr int NBMAX = (N == 32) ? 2 : 1;
  constexpr int NVMAX = (N == 32) ? 4 : 1;
  const int MAXSW = (N == 32) ? 10 : ((N == 16) ? 9 : 5);
  for (int e = tid; e < N * N; e += 128) {
    const int r = e >> NL, c = e & (N - 1);
    V[r * 36 + c] = (r == c) ? 1.0f : 0.0f;
  }
  __syncthreads();
  const int cp = tid & (NP - 1);
  const bool hact = (N == 32) ? true : (tid < NP * NP);
  const bool vact = (N >= 16) ? true : (tid < N * NP);
  for (int sw = 0; sw < MAXSW; ++sw) {
    for (int rd = 0; rd < N - 1; ++rd) {
      int q0, q1; pairpq<N>(cp, rd, q0, q1);
      float cc_, cs_;
      jrot(H[q0 * 37], H[q1 * 37], H[q0 * 36 + q1], cc_, cs_);
      float o00[NBMAX], o01[NBMAX], o10[NBMAX], o11[NBMAX];
      int P0[NBMAX], P1[NBMAX];
      #pragma unroll
      for (int bi = 0; bi < NBMAX; ++bi) {
        if (bi == 0 && !hact) continue;
        const int rp = (N == 32) ? ((tid >> 4) + 8 * bi) : ((N == 16) ? (tid >> 3) : (tid >> 1));
        int p0, p1; pairpq<N>(rp, rd, p0, p1);
        float cr_, sr_;
        jrot(H[p0 * 37], H[p1 * 37], H[p0 * 36 + p1], cr_, sr_);
        const float a  = H[p0 * 36 + q0], b = H[p0 * 36 + q1];
        const float c2 = H[p1 * 36 + q0], d = H[p1 * 36 + q1];
        const float t1 = cr_ * a - sr_ * c2, t2 = cr_ * b - sr_ * d;
        const float u1 = sr_ * a + cr_ * c2, u2 = sr_ * b + cr_ * d;
        o00[bi] = cc_ * t1 - cs_ * t2; o01[bi] = cs_ * t1 + cc_ * t2;
        o10[bi] = cc_ * u1 - cs_ * u2; o11[bi] = cs_ * u1 + cc_ * u2;
        P0[bi] = p0; P1[bi] = p1;
      }
      float v0[NVMAX], v1[NVMAX];
      #pragma unroll
      for (int vi = 0; vi < NVMAX; ++vi) {
        if (vi == 0 && !vact) continue;
        const int row = (N == 32) ? ((tid >> 4) + 8 * vi) : ((N == 16) ? (tid >> 3) : (tid >> 1));
        const float a0 = V[row * 36 + q0], a1 = V[row * 36 + q1];
        v0[vi] = cc_ * a0 - cs_ * a1; v1[vi] = cs_ * a0 + cc_ * a1;
      }
      __syncthreads();
      #pragma unroll
      for (int bi = 0; bi < NBMAX; ++bi) {
        if (bi == 0 && !hact) continue;
        H[P0[bi] * 36 + q0] = o00[bi]; H[P0[bi] * 36 + q1] = o01[bi];
        H[P1[bi] * 36 + q0] = o10[bi]; H[P1[bi] * 36 + q1] = o11[bi];
      }
      #pragma unroll
      for (int vi = 0; vi < NVMAX; ++vi) {
        if (vi == 0 && !vact) continue;
        const int row = (N == 32) ? ((tid >> 4) + 8 * vi) : ((N == 16) ? (tid >> 3) : (tid >> 1));
        V[row * 36 + q0] = v0[vi]; V[row * 36 + q1] = v1[vi];
      }
      __syncthreads();
    }
    if (N >= 16) {
      float offs = 0.0f, dia = 0.0f;
      for (int e = tid; e < N * N; e += 128) {
        const int r = e >> NL, c = e & (N - 1);
        const float v_ = H[r * 36 + c];
        if (r == c) dia += v_ * v_; else offs += v_ * v_;
      }
      for (int mk = 32; mk; mk >>= 1) { offs += __shfl_xor(offs, mk); dia += __shfl_xor(dia, mk); }
      if ((tid & 63) == 0) { red[(tid >> 6) * 2] = offs; red[(tid >> 6) * 2 + 1] = dia; }
      __syncthreads();
      const float to = red[0] + red[2];
      const float td = red[1] + red[3];
      const bool done = (to <= 1e-12f * td);
      __syncthreads();
      if (done) break;
    }
  }
  __syncthreads();
}

// G(+)= A^T A over 'nrows' stride-36 rows of A, mcols in {16,32}; float4 on column quads
__device__ __forceinline__ void gram_cols(float* __restrict__ G, const float* __restrict__ A,
                                          int nrows, int mcols, bool init, int tid)
{
  const int q4 = mcols >> 2;
  const int q4log = (mcols == 32) ? 3 : 2;
  const int nel = mcols * q4;
  const float4* A4 = (const float4*)A;
  float4* G4 = (float4*)G;
  for (int e = tid; e < nel; e += 128) {
    const int c2q = e & (q4 - 1);
    const int c1 = e >> q4log;
    float ax = 0.f, ay = 0.f, az = 0.f, aw = 0.f;
    for (int r = 0; r < nrows; ++r) {
      const float a1 = A[r * 36 + c1];
      const float4 a2 = A4[r * 9 + c2q];
      ax += a1 * a2.x; ay += a1 * a2.y; az += a1 * a2.z; aw += a1 * a2.w;
    }
    float4* gp = G4 + c1 * 9 + c2q;
    if (init) { float4 o; o.x = ax; o.y = ay; o.z = az; o.w = aw; *gp = o; }
    else { float4 o = *gp; o.x += ax; o.y += ay; o.z += az; o.w += aw; *gp = o; }
  }
  __syncthreads();
}

// absorb column i1 of row j into BIGT[(rr-rr0)*dbw+db][ua] (stride 36), rr in [rr0,rr1)
__device__ __forceinline__ void absorb_T(const float* __restrict__ Tg, const float* __restrict__ poolS,
    float* __restrict__ BIGT, float* __restrict__ ATile, const int* __restrict__ xi,
    int i1, int j, int U, int Dd, int rr0, int rr1, int tid)
{
  const int bd = (i1 == 5) ? 1 : 4;
  const int dbw = Dd * bd;
  const int mt_ = U * 4;
  const int ph = xi[i1 * 6 + j];
  const float* tb = Tg + (size_t)(i1 * 6 + j) * 512;
  for (int e = tid; e < 256; e += 128) ATile[e] = tb[e * 2 + ph];
  __syncthreads();
  const int mlog = (mt_ == 32) ? 5 : 4;
  const int dblog = 31 - __clz(dbw);
  const int bdlog = (bd == 4) ? 2 : 0;
  const int nel = mt_ * dbw * (rr1 - rr0);
  for (int e = tid; e < nel; e += 128) {
    const int ua = e & (mt_ - 1);
    const int db = (e >> mlog) & (dbw - 1);
    const int rr = rr0 + (e >> (mlog + dblog));
    const int u = ua >> 2, a = ua & 3;
    const int d_ = db >> bdlog, b = db & (bd - 1);
    const float* op = poolS + u * 33 + d_;
    const float4 av = *(const float4*)(ATile + a * 64 + rr * 16 + b * 4);
    BIGT[((rr - rr0) * dbw + db) * 36 + ua] = op[0] * av.x + op[8] * av.y + op[16] * av.z + op[24] * av.w;
  }
  __syncthreads();
}

// ============ kernel 2: one sample per 128-thread workgroup ============
__global__ __launch_bounds__(128, 2) void peps_kernel(
    const float* __restrict__ Tg, const int* __restrict__ x,
    float* __restrict__ proj, float* __restrict__ out)
{
  __shared__ float pool[6 * 264];   // [i][u<=8 stride33][x=4 stride8][d<=8]
  __shared__ float CUR[1152];       // mt: rows (u*4+rr)<=32, stride 36, cols m<=32
  __shared__ float BIGT[2304];      // mb^T half: rows (rr*dbw+db)<=64 stride 36, cols m
  __shared__ float GbM[1152];       // Gb (or Gt for q-path); m-path: Gb@0, Gt@576 (16x36 each)
  __shared__ float TM[1152];        // T / R2@0+T1@576 / eigvecs V
  __shared__ float GM[1152];        // G / H (diagonalized in place)
  __shared__ float ATile[256];
  __shared__ float PdL[256], PuL[256];  // [mrow][8]
  __shared__ float red[4];
  __shared__ int isel[8];
  __shared__ float sinvv[8], sdiv[8];
  __shared__ int xi[36];
  __shared__ float vvec[36], vvec2[36];

  const int s = blockIdx.x;
  const int tid = threadIdx.x;
  if (tid < 36) xi[tid] = x[s * 36 + tid];
  __syncthreads();

  for (int sweep = 0; sweep < 2; ++sweep) {
    // --- init boundary MPS from row j=0 ---
    for (int i2 = 0; i2 < 6; ++i2) {
      const int ad = (i2 == 0) ? 1 : 4, bd = (i2 == 5) ? 1 : 4;
      const int bdlog = (bd == 4) ? 2 : 0;
      const int ph = xi[i2 * 6];
      const float* tb = Tg + (size_t)(i2 * 6) * 512;
      const int nel = ad * 4 * bd;
      for (int e = tid; e < nel; e += 128) {
        const int b = e & (bd - 1);
        const int rr = (e >> bdlog) & 3;
        const int a = e >> (bdlog + 2);
        pool[i2 * 264 + a * 33 + rr * 8 + b] = tb[(a * 64 + rr * 16 + b * 4) * 2 + ph];
      }
    }
    __syncthreads();

    for (int j = 1; j <= 4; ++j) {
      const int jj = (j > 1) ? 1 : 0;
      // absorb column 0 into CUR (4 rows x 16 cols)
      {
        const int ph = xi[j];          // site (0,j)
        const float* tb = Tg + (size_t)j * 512;
        for (int e = tid; e < 256; e += 128) ATile[e] = tb[e * 2 + ph];
        __syncthreads();
        for (int e = tid; e < 64; e += 128) {
          const int db = e & 15;
          const int rr = e >> 4;
          const int d_ = db >> 2, b = db & 3;
          const float* op = pool + d_;  // slot 0, u=0
          const float4 av = *(const float4*)(ATile + rr * 16 + b * 4);  // a=0
          CUR[rr * 36 + db] = op[0] * av.x + op[8] * av.y + op[16] * av.z + op[24] * av.w;
        }
        __syncthreads();
      }

      for (int i = 0; i < 5; ++i) {
        const int m = g_mtab[jj][i], cb = g_cbtab[i], ucur = g_ucurtab[i], dn = g_dntab[jj][i];
        const int p = ucur * 4, path = g_path[jj][i];
        const int U1 = g_uprev[jj][i + 1], Dd1 = g_dprev[jj][i + 1];
        const bool two = (dn == 32);
        const int cblog = (cb == 8) ? 3 : 2;
        const int mq4 = m >> 2;
        float* projb = proj + (size_t)s * 6400 + g_offtab[j - 1][i];

        if (sweep == 0) {
          if (path == 2) {
            // ---- q-side (i=4): G = mb^T Gt mb (4x4) ----
            absorb_T(Tg, pool + (i + 1) * 264, BIGT, ATile, xi, i + 1, j, U1, Dd1, 0, 4, tid);
            gram_cols(GbM, CUR, p, m, true, tid);   // Gt (16x16)
            for (int e = tid; e < 64; e += 128) {   // T1 = Gt*mb (16x4)
              const int r = e & 3, k = e >> 2;
              float acc = 0.f;
              const float4* G4 = (const float4*)GbM;
              const float4* B4 = (const float4*)BIGT;
              for (int lq = 0; lq < 4; ++lq) {
                const float4 g = G4[k * 9 + lq], b = B4[r * 9 + lq];
                acc += g.x * b.x + g.y * b.y + g.z * b.z + g.w * b.w;
              }
              TM[k * 36 + r] = acc;
            }
            __syncthreads();
            for (int e = tid; e < 16; e += 128) {   // G = mb^T * T1 (4x4)
              const int c = e & 3, r = e >> 2;
              float acc = 0.f;
              for (int k = 0; k < 16; ++k) acc += BIGT[r * 36 + k] * TM[k * 36 + c];
              GM[r * 36 + c] = acc;
            }
            __syncthreads();
            jacobi_pb<4>(GM, TM + 576, red, tid);
          } else if (path == 0) {
            // ---- p-side: G = mt Gb mt^T (p x p), no Cholesky ----
            if (!two) {
              absorb_T(Tg, pool + (i + 1) * 264, BIGT, ATile, xi, i + 1, j, U1, Dd1, 0, 4, tid);
              gram_cols(GbM, BIGT, 4 * dn, m, true, tid);
            } else {
              absorb_T(Tg, pool + (i + 1) * 264, BIGT, ATile, xi, i + 1, j, U1, Dd1, 0, 2, tid);
              gram_cols(GbM, BIGT, 2 * dn, m, true, tid);
              absorb_T(Tg, pool + (i + 1) * 264, BIGT, ATile, xi, i + 1, j, U1, Dd1, 2, 4, tid);
              gram_cols(GbM, BIGT, 2 * dn, m, false, tid);
            }
            const int q4log = (m == 32) ? 3 : 2;
            for (int e = tid; e < p * mq4; e += 128) {  // T = mt*Gb (p x m)
              const int lq = e & (mq4 - 1), pr = e >> q4log;
              float ax = 0.f, ay = 0.f, az = 0.f, aw = 0.f;
              const float4* G4 = (const float4*)GbM;
              for (int k = 0; k < m; ++k) {
                const float a1 = CUR[pr * 36 + k];
                const float4 g = G4[k * 9 + lq];
                ax += a1 * g.x; ay += a1 * g.y; az += a1 * g.z; aw += a1 * g.w;
              }
              float4 o; o.x = ax; o.y = ay; o.z = az; o.w = aw;
              ((float4*)TM)[pr * 9 + lq] = o;
            }
            __syncthreads();
            const int plog = (p == 32) ? 5 : ((p == 16) ? 4 : 2);
            for (int e = tid; e < p * p; e += 128) {    // G = T*mt^T (p x p)
              const int pc = e & (p - 1), pr = e >> plog;
              float acc = 0.f;
              const float4* T4 = (const float4*)TM;
              const float4* C4 = (const float4*)CUR;
              for (int lq = 0; lq < mq4; ++lq) {
                const float4 t = T4[pr * 9 + lq], c = C4[pc * 9 + lq];
                acc += t.x * c.x + t.y * c.y + t.z * c.z + t.w * c.w;
              }
              GM[pr * 36 + pc] = acc;
            }
            __syncthreads();
            if (p == 4)       jacobi_pb<4>(GM, TM, red, tid);
            else if (p == 16) jacobi_pb<16>(GM, TM, red, tid);
            else              jacobi_pb<32>(GM, TM, red, tid);
          } else {
            // ---- m-side (jj0 i=2,3): Gt, Gb, chol(Gb), H = R2 Gt R2^T (16x16) ----
            absorb_T(Tg, pool + (i + 1) * 264, BIGT, ATile, xi, i + 1, j, U1, Dd1, 0, 4, tid);
            gram_cols(GbM + 576, CUR, p, m, true, tid);     // Gt
            gram_cols(GbM, BIGT, 4 * dn, m, true, tid);     // Gb
            // cholesky Gb -> R2 (TM[0:576]) with zero-skip
            if (tid < 64) {
              float v_ = (tid < 16) ? GbM[tid * 37] : -3.0e38f;
              for (int mk = 32; mk; mk >>= 1) v_ = fmaxf(v_, __shfl_xor(v_, mk));
              if (tid == 0) red[0] = v_;
            }
            __syncthreads();
            const float thr = 1e-10f * red[0] + 1e-35f;
            for (int k = 0; k < 16; ++k) {
              const float dk = GbM[k * 37];
              const float rs = (dk > thr) ? (1.0f / sqrtf(dk)) : 0.0f;
              if (tid < 16) TM[k * 36 + tid] = GbM[k * 36 + tid] * rs;
              __syncthreads();
              const int rows = 15 - k;
              for (int e = tid; e < rows * 16; e += 128) {
                const int ii = k + 1 + (e >> 4), jc = e & 15;
                GbM[ii * 36 + jc] -= TM[k * 36 + ii] * TM[k * 36 + jc];
              }
              __syncthreads();
            }
            for (int e = tid; e < 64; e += 128) {   // T1 = R2*Gt -> TM+576
              const int jq = e & 3, k = e >> 2;
              float ax = 0.f, ay = 0.f, az = 0.f, aw = 0.f;
              const float4* Gt4 = (const float4*)(GbM + 576);
              for (int l = 0; l < 16; ++l) {
                const float r2 = TM[k * 36 + l];
                const float4 g = Gt4[l * 9 + jq];
                ax += r2 * g.x; ay += r2 * g.y; az += r2 * g.z; aw += r2 * g.w;
              }
              float4 o; o.x = ax; o.y = ay; o.z = az; o.w = aw;
              ((float4*)(TM + 576))[k * 9 + jq] = o;
            }
            __syncthreads();
            for (int e = tid; e < 256; e += 128) {  // H = T1*R2^T -> GM
              const int k2 = e & 15, k = e >> 4;
              float acc = 0.f;
              const float4* T14 = (const float4*)(TM + 576);
              const float4* R24 = (const float4*)TM;
              for (int lq = 0; lq < 4; ++lq) {
                const float4 t = T14[k * 9 + lq], r = R24[k2 * 9 + lq];
                acc += t.x * r.x + t.y * r.y + t.z * r.z + t.w * r.w;
              }
              GM[k * 36 + k2] = acc;
            }
            __syncthreads();
            jacobi_pb<16>(GM, TM + 576, red, tid);
          }

          // ---- top-cb selection + scales ----
          const int N = (path == 2) ? 4 : ((path == 1) ? 16 : p);
          if (tid < 64) {
            float v_ = (tid < N) ? GM[tid * 37] : -3.0e38f;
            int ix = tid;
            for (int t = 0; t < cb; ++t) {
              float bv = v_; int bi = ix;
              for (int mk = 32; mk; mk >>= 1) {
                const float ov = __shfl_xor(bv, mk);
                const int oi = __shfl_xor(bi, mk);
                if (ov > bv || (ov == bv && oi < bi)) { bv = ov; bi = oi; }
              }
              if (tid == 0) isel[t] = bi;
              if (ix == bi) v_ = -3.0e38f;
            }
          }
          __syncthreads();
          if (tid < cb) {
            const float lam = GM[isel[tid] * 37];
            const float s_ = sqrtf(fmaxf(lam, 0.0f));
            sinvv[tid] = 1.0f / sqrtf(s_ + 1e-12f);
            sdiv[tid]  = 1.0f / fmaxf(s_, 1e-25f);
          }
          __syncthreads();

          // ---- projectors ----
          if (path == 0) {
            // Pu = mt^T U sinv ; Pd = Gb Pu / s   (U cols in TM)
            for (int e = tid; e < m * cb; e += 128) {
              const int k = e & (cb - 1), mrow = e >> cblog;
              const int a = isel[k];
              float acc = 0.f;
              for (int pr = 0; pr < p; ++pr) acc += CUR[pr * 36 + mrow] * TM[pr * 36 + a];
              PuL[mrow * 8 + k] = acc * sinvv[k];
            }
            __syncthreads();
            for (int e = tid; e < m * cb; e += 128) {
              const int k = e & (cb - 1), mrow = e >> cblog;
              float acc = 0.f;
              for (int l = 0; l < m; ++l) acc += GbM[mrow * 36 + l] * PuL[l * 8 + k];
              PdL[mrow * 8 + k] = acc * sdiv[k];
            }
            __syncthreads();
          } else if (path == 2) {
            // Pd = mb V sinv ; Pu = Gt Pd / s   (V in TM+576, Gt in GbM)
            for (int e = tid; e < m * cb; e += 128) {
              const int k = e & (cb - 1), mrow = e >> cblog;
              const int a = isel[k];
              float acc = 0.f;
              for (int r = 0; r < 4; ++r) acc += BIGT[r * 36 + mrow] * TM[576 + r * 36 + a];
              PdL[mrow * 8 + k] = acc * sinvv[k];
            }
            __syncthreads();
            for (int e = tid; e < m * cb; e += 128) {
              const int k = e & (cb - 1), mrow = e >> cblog;
              float acc = 0.f;
              for (int l = 0; l < m; ++l) acc += GbM[mrow * 36 + l] * PdL[l * 8 + k];
              PuL[mrow * 8 + k] = acc * sdiv[k];
            }
            __syncthreads();
          } else {
            // Pd = R2^T V sinv ; Pu = Gt Pd / s  (R2 in TM[0:576], V in TM+576, Gt in GbM+576)
            for (int e = tid; e < m * cb; e += 128) {
              const int k = e & (cb - 1), mrow = e >> cblog;
              const int a = isel[k];
              float acc = 0.f;
              for (int t = 0; t < 16; ++t) acc += TM[t * 36 + mrow] * TM[576 + t * 36 + a];
              PdL[mrow * 8 + k] = acc * sinvv[k];
            }
            __syncthreads();
            for (int e = tid; e < m * cb; e += 128) {
              const int k = e & (cb - 1), mrow = e >> cblog;
              float acc = 0.f;
              for (int l = 0; l < m; ++l) acc += GbM[576 + mrow * 36 + l] * PdL[l * 8 + k];
              PuL[mrow * 8 + k] = acc * sdiv[k];
            }
            __syncthreads();
          }
          // store perturbed projectors (ws slot preloaded with ETA*mlp)
          for (int e = tid; e < m * cb; e += 128)
            projb[e] += PdL[(e >> cblog) * 8 + (e & (cb - 1))];
          for (int e = tid; e < m * cb; e += 128)
            projb[m * cb + e] += PuL[(e >> cblog) * 8 + (e & (cb - 1))];
        } else {
          // ---- sweep 2: load perturbed projectors + stage mb (B-half for two-pass) ----
          for (int e = tid; e < m * cb; e += 128)
            PdL[(e >> cblog) * 8 + (e & (cb - 1))] = projb[e];
          for (int e = tid; e < m * cb; e += 128)
            PuL[(e >> cblog) * 8 + (e & (cb - 1))] = projb[m * cb + e];
          __syncthreads();
          if (!two) absorb_T(Tg, pool + (i + 1) * 264, BIGT, ATile, xi, i + 1, j, U1, Dd1, 0, 4, tid);
          else      absorb_T(Tg, pool + (i + 1) * 264, BIGT, ATile, xi, i + 1, j, U1, Dd1, 2, 4, tid);
        }

        // ---- common: Bn[i] = Tt*Pd -> pool[i]; Bn[i+1] = Pu^T applied to mb -> CUR (or pool[5]) ----
        {
          const int nel = ucur * 4 * cb;
          const float4* C4 = (const float4*)CUR;
          for (int e = tid; e < nel; e += 128) {
            const int cc = e & (cb - 1);
            const int rr = (e >> cblog) & 3;
            const int u = e >> (cblog + 2);
            const int row = u * 4 + rr;
            float acc = 0.f;
            for (int mq = 0; mq < mq4; ++mq) {
              const float4 cv = C4[row * 9 + mq];
              acc += cv.x * PdL[(mq * 4 + 0) * 8 + cc] + cv.y * PdL[(mq * 4 + 1) * 8 + cc]
                   + cv.z * PdL[(mq * 4 + 2) * 8 + cc] + cv.w * PdL[(mq * 4 + 3) * 8 + cc];
            }
            pool[i * 264 + u * 33 + rr * 8 + cc] = acc;
          }
          __syncthreads();

          const int dnlog = 31 - __clz(dn);
          auto bn1 = [&](int rr0, int nloc) {
            const int ne2 = cb * nloc * dn;
            const float4* B4 = (const float4*)BIGT;
            for (int e = tid; e < ne2; e += 128) {
              const int dd = e & (dn - 1);
              const int t = e >> dnlog;
              const int rrL = t & (nloc - 1);
              const int cc = t >> ((nloc == 4) ? 2 : 1);
              const int row = rrL * dn + dd;
              float acc = 0.f;
              for (int mq = 0; mq < mq4; ++mq) {
                const float4 bv = B4[row * 9 + mq];
                acc += bv.x * PuL[(mq * 4 + 0) * 8 + cc] + bv.y * PuL[(mq * 4 + 1) * 8 + cc]
                     + bv.z * PuL[(mq * 4 + 2) * 8 + cc] + bv.w * PuL[(mq * 4 + 3) * 8 + cc];
              }
              if (i < 4) CUR[(cc * 4 + rr0 + rrL) * 36 + dd] = acc;
              else       pool[5 * 264 + cc * 33 + (rr0 + rrL) * 8] = acc;
            }
            __syncthreads();
          };
          if (!two) {
            bn1(0, 4);
          } else {
            bn1(2, 2);
            absorb_T(Tg, pool + (i + 1) * 264, BIGT, ATile, xi, i + 1, j, U1, Dd1, 0, 2, tid);
            bn1(0, 2);
          }
        }
      }
    }

    if (sweep == 1) {
      // ---- finalize: scalar = prod_i C_i ----
      if (tid == 0) vvec[0] = 1.0f;
      __syncthreads();
      for (int i = 0; i < 6; ++i) {
        const int ad = (i == 0) ? 1 : 4, bd = (i == 5) ? 1 : 4;
        const int adlog = (ad == 4) ? 2 : 0, bdlog = (bd == 4) ? 2 : 0;
        const int rows = g_ufin[i] * ad, cols = g_dfin[i] * bd;
        const int clog = 31 - __clz(cols);
        const int ph = xi[i * 6 + 5];
        const float* tb = Tg + (size_t)(i * 6 + 5) * 512;
        for (int e = tid; e < 256; e += 128) ATile[e] = tb[e * 2 + ph];
        __syncthreads();
        for (int e = tid; e < rows * cols; e += 128) {
          const int col = e & (cols - 1);
          const int ua = e >> clog;
          const int u = ua >> adlog, a = ua & (ad - 1);
          const int d_ = col >> bdlog, b = col & (bd - 1);
          const float* fb = pool + i * 264 + u * 33 + d_;
          const float4 av = *(const float4*)(ATile + a * 64 + b * 4);  // R = 0
          GM[ua * 36 + col] = fb[0] * av.x + fb[8] * av.y + fb[16] * av.z + fb[24] * av.w;
        }
        __syncthreads();
        if (tid < cols) {
          float acc = 0.f;
          for (int r_ = 0; r_ < rows; ++r_) acc += vvec[r_] * GM[r_ * 36 + tid];
          vvec2[tid] = acc;
        }
        __syncthreads();
        if (tid < cols) vvec[tid] = vvec2[tid];
        __syncthreads();
      }
      if (tid == 0) out[s] = vvec[0];
    }
  }
}

extern "C" void kernel_launch(void* const* d_in, const int* in_sizes, int n_in,
                              void* d_out, int out_size, void* d_ws, size_t ws_size,
                              hipStream_t stream) {
  const float* Tg = (const float*)d_in[0];
  const float* W1 = (const float*)d_in[1];
  const float* b1 = (const float*)d_in[2];
  const float* W2 = (const float*)d_in[3];
  const float* b2 = (const float*)d_in[4];
  const int*   x  = (const int*)d_in[5];
  float* out = (float*)d_out;
  float* proj = (float*)d_ws;   // 1024*6400 floats: ETA*mlp then += projectors
  (void)in_sizes; (void)n_in; (void)out_size; (void)ws_size;

  mlp_kernel<<<dim3(128), dim3(256), 0, stream>>>(W1, b1, W2, b2, x, proj);
  peps_kernel<<<dim3(1024), dim3(128), 0, stream>>>(Tg, x, proj, out);
}